// Round 3
// baseline (116.396 us; speedup 1.0000x reference)
//
#include <hip/hip_runtime.h>

#define B  4
#define TE 512
#define TD 256
#define DE 512
#define U  128

#define RCPF(x)  __builtin_amdgcn_rcpf(x)
#define EXP2F(x) __builtin_amdgcn_exp2f(x)

#define ROWFMA(ar, xr) \
    ar.x += xr.x*w0.x + xr.y*w1.x + xr.z*w2.x + xr.w*w3.x; \
    ar.y += xr.x*w0.y + xr.y*w1.y + xr.z*w2.y + xr.w*w3.y; \
    ar.z += xr.x*w0.z + xr.y*w1.z + xr.z*w2.z + xr.w*w3.z; \
    ar.w += xr.x*w0.w + xr.y*w1.w + xr.z*w2.w + xr.w*w3.w;

#define ADD4(d, s) d.x += s.x; d.y += s.y; d.z += s.z; d.w += s.w;

// ---------------------------------------------------------------------------
// Encoder projection only, output in EXP DOMAIN: E = exp(2*(enc@W1+b1)),
// TRANSPOSED as encT[b][u][e] (LDS transpose; both global sides coalesced).
// 256 blocks (1/CU, perfectly balanced), 512 threads, 8 rows/block.
// 8-way K-split: wave ds owns d-slice [64*ds, 64*ds+64); each thread owns
// 4 rows (g, g+2, g+4, g+6). W1 streamed exactly once per block.
// ---------------------------------------------------------------------------
__global__ __launch_bounds__(512) void proj_enc_kernel(
        const float* __restrict__ enc, const float* __restrict__ W1w,
        const float* __restrict__ W1b, float* __restrict__ encT){
    __shared__ float4 Xs[8 * 128];      // 8 rows x 512 f32 = 16 KB
    __shared__ float4 Ps[7 * 8 * 32];   // partials [ds-1][row][q] = 28 KB
    float* T = (float*)Xs;              // aliased transpose buffer
    const int tid = threadIdx.x;
    const int r0 = blockIdx.x * 8;

    // stage 8 rows (1024 float4), coalesced, 2 per thread
    const float4* Xg = (const float4*)(enc + (size_t)r0 * 512);
    Xs[tid]       = Xg[tid];
    Xs[tid + 512] = Xg[tid + 512];
    __syncthreads();

    const int q  = tid & 31;          // u-quad: u0 = 4q
    const int g  = (tid >> 5) & 1;    // rows g, g+2, g+4, g+6
    const int ds = tid >> 6;          // d-slice (one per wave), 64 d each
    const float4* W4 = (const float4*)W1w;   // row d = 32 float4

    float4 a0, a1, a2, a3;
    a0 = a1 = a2 = a3 = make_float4(0.f, 0.f, 0.f, 0.f);

    const int dbase = ds * 64;
    #pragma unroll 4
    for (int dd = 0; dd < 64; dd += 4){
        const int d0 = dbase + dd;
        const int xq = d0 >> 2;
        float4 x0 = Xs[(g + 0) * 128 + xq];     // LDS broadcast
        float4 x1 = Xs[(g + 2) * 128 + xq];
        float4 x2 = Xs[(g + 4) * 128 + xq];
        float4 x3 = Xs[(g + 6) * 128 + xq];
        float4 w0 = W4[(d0 + 0) * 32 + q];
        float4 w1 = W4[(d0 + 1) * 32 + q];
        float4 w2 = W4[(d0 + 2) * 32 + q];
        float4 w3 = W4[(d0 + 3) * 32 + q];
        ROWFMA(a0, x0)
        ROWFMA(a1, x1)
        ROWFMA(a2, x2)
        ROWFMA(a3, x3)
    }

    if (ds){
        Ps[((ds-1)*8 + g + 0)*32 + q] = a0;
        Ps[((ds-1)*8 + g + 2)*32 + q] = a1;
        Ps[((ds-1)*8 + g + 4)*32 + q] = a2;
        Ps[((ds-1)*8 + g + 6)*32 + q] = a3;
    }
    __syncthreads();                           // partials ready; Xs reads done

    if (ds == 0){
        #pragma unroll
        for (int p = 0; p < 7; ++p){
            float4 r;
            r = Ps[(p*8 + g + 0)*32 + q]; ADD4(a0, r)
            r = Ps[(p*8 + g + 2)*32 + q]; ADD4(a1, r)
            r = Ps[(p*8 + g + 4)*32 + q]; ADD4(a2, r)
            r = Ps[(p*8 + g + 6)*32 + q]; ADD4(a3, r)
        }
        float4 bq = ((const float4*)W1b)[q];
        ADD4(a0, bq) ADD4(a1, bq) ADD4(a2, bq) ADD4(a3, bq)

        const float C2 = 2.8853900817779268f;  // 2*log2(e)
        a0.x = EXP2F(a0.x*C2); a0.y = EXP2F(a0.y*C2); a0.z = EXP2F(a0.z*C2); a0.w = EXP2F(a0.w*C2);
        a1.x = EXP2F(a1.x*C2); a1.y = EXP2F(a1.y*C2); a1.z = EXP2F(a1.z*C2); a1.w = EXP2F(a1.w*C2);
        a2.x = EXP2F(a2.x*C2); a2.y = EXP2F(a2.y*C2); a2.z = EXP2F(a2.z*C2); a2.w = EXP2F(a2.w*C2);
        a3.x = EXP2F(a3.x*C2); a3.y = EXP2F(a3.y*C2); a3.z = EXP2F(a3.z*C2); a3.w = EXP2F(a3.w*C2);

        // T[u][e_local], u-stride 9 (pad breaks power-of-2 banks)
        T[(4*q+0)*9 + g + 0] = a0.x; T[(4*q+1)*9 + g + 0] = a0.y;
        T[(4*q+2)*9 + g + 0] = a0.z; T[(4*q+3)*9 + g + 0] = a0.w;
        T[(4*q+0)*9 + g + 2] = a1.x; T[(4*q+1)*9 + g + 2] = a1.y;
        T[(4*q+2)*9 + g + 2] = a1.z; T[(4*q+3)*9 + g + 2] = a1.w;
        T[(4*q+0)*9 + g + 4] = a2.x; T[(4*q+1)*9 + g + 4] = a2.y;
        T[(4*q+2)*9 + g + 4] = a2.z; T[(4*q+3)*9 + g + 4] = a2.w;
        T[(4*q+0)*9 + g + 6] = a3.x; T[(4*q+1)*9 + g + 6] = a3.y;
        T[(4*q+2)*9 + g + 6] = a3.z; T[(4*q+3)*9 + g + 6] = a3.w;
    }
    __syncthreads();                           // T ready

    if (tid < 128){
        const int u  = tid;
        const int bb = r0 >> 9;        // 512 rows per batch
        const int et = r0 & 511;       // e-tile base
        float4 lo = make_float4(T[u*9+0], T[u*9+1], T[u*9+2], T[u*9+3]);
        float4 hi = make_float4(T[u*9+4], T[u*9+5], T[u*9+6], T[u*9+7]);
        float4* row = (float4*)encT + (size_t)(bb*U + u)*128 + (et >> 2);
        row[0] = lo; row[1] = hi;
    }
}

// ---------------------------------------------------------------------------
// Score + softmax with INTEGRATED dec projection (exp-domain).
// Each block (b, t-quad) first computes Ed = exp(2*(dec@W2+b2)) for its own
// 4 t-rows (4-way K-split over waves; W2 stream hides under the trans-bound
// main loop), then the exp-factorized score:
//   logits[e] = sum_u (-2*V_u) * rcp(Ea[u][e]*Ed[t][u] + 1)
// (the e-independent constant cancels in softmax).
// 512 threads: main loop has each thread handle ALL 4 t's for its 4 e's,
// u quarter-split across waves (uh), partials combined in LDS.
// ---------------------------------------------------------------------------
#define TANH_ACC(s, dv) \
    s.x += wv * RCPF(fmaf(A.x, dv, 1.0f)); \
    s.y += wv * RCPF(fmaf(A.y, dv, 1.0f)); \
    s.z += wv * RCPF(fmaf(A.z, dv, 1.0f)); \
    s.w += wv * RCPF(fmaf(A.w, dv, 1.0f));

__global__ __launch_bounds__(512) void score_kernel(
        const float* __restrict__ encT, const float* __restrict__ dec,
        const float* __restrict__ W2w, const float* __restrict__ W2b,
        const float* __restrict__ Vw, float* __restrict__ attn_out){
    __shared__ float4 Xd[4 * 128];       // raw dec rows t0..t0+3, 8 KB
    __shared__ float4 dp4[128];          // Ed rows t0..t0+3 (exp domain), 2 KB
    __shared__ float4 vv4[32];           // -2*V (128 f32)
    __shared__ float4 Pp[3 * 4 * 128];   // partials [..][t][eq] = 24 KB (reused)
    __shared__ float redm[8], reds[8];   // [t][wave-half]
    const float* dpf = (const float*)dp4;
    const float* vvf = (const float*)vv4;
    const int tid = threadIdx.x;
    const int b  = blockIdx.x >> 6;
    const int t0 = (blockIdx.x & 63) * 4;

    // stage raw dec rows (512 float4, 1/thread) + V
    Xd[tid] = ((const float4*)dec)[(size_t)(b*TD + t0) * 128 + tid];
    if (tid < 32){
        float4 v = ((const float4*)Vw)[tid];
        vv4[tid] = make_float4(-2.f*v.x, -2.f*v.y, -2.f*v.z, -2.f*v.w);
    }
    __syncthreads();

    // ---- dec-proj: q = tid&31 (u-quad), g = (tid>>5)&3 (t-row), ds = tid>>7
    {
        const int q  = tid & 31;
        const int g  = (tid >> 5) & 3;
        const int ds = tid >> 7;          // d-quarter (wave-pair uniform)
        const float4* W24 = (const float4*)W2w;
        const float4* Xrow = Xd + g * 128;
        float4 acc = make_float4(0.f, 0.f, 0.f, 0.f);
        const int dbase = ds * 128;
        #pragma unroll 2
        for (int dd = 0; dd < 128; dd += 4){
            const int d0 = dbase + dd;
            float4 xr = Xrow[d0 >> 2];
            float4 w0 = W24[(d0 + 0) * 32 + q];
            float4 w1 = W24[(d0 + 1) * 32 + q];
            float4 w2 = W24[(d0 + 2) * 32 + q];
            float4 w3 = W24[(d0 + 3) * 32 + q];
            ROWFMA(acc, xr)
        }
        if (ds) Pp[((ds-1)*4 + g)*32 + q] = acc;
        __syncthreads();
        if (ds == 0){                     // tid<128: exactly (g,q) coverage
            #pragma unroll
            for (int p = 0; p < 3; ++p){
                float4 r = Pp[(p*4 + g)*32 + q]; ADD4(acc, r)
            }
            float4 bq = ((const float4*)W2b)[q];
            ADD4(acc, bq)
            const float C2 = 2.8853900817779268f;
            acc.x = EXP2F(acc.x*C2); acc.y = EXP2F(acc.y*C2);
            acc.z = EXP2F(acc.z*C2); acc.w = EXP2F(acc.w*C2);
            dp4[g*32 + q] = acc;          // dpf[t*128 + u] layout
        }
        __syncthreads();
    }

    // ---- main score loop
    const int uh = tid >> 7;         // u-quarter 0..3
    const int eq = tid & 127;        // e-quad: e0 = 4*eq
    const int u0 = uh * 32;

    const float4* E  = (const float4*)encT + (size_t)b*U*128 + (size_t)u0*128 + eq;
    const float* dt0 = dpf + 0*128 + u0;
    const float* dt1 = dpf + 1*128 + u0;
    const float* dt2 = dpf + 2*128 + u0;
    const float* dt3 = dpf + 3*128 + u0;
    const float* vv  = vvf + u0;

    float4 s0, s1, s2, s3;
    s0 = s1 = s2 = s3 = make_float4(0.f, 0.f, 0.f, 0.f);

    #pragma unroll 4
    for (int u = 0; u < 32; ++u){
        float4 A = E[(size_t)u * 128];        // coalesced across e-lanes
        float d0 = dt0[u], d1 = dt1[u], d2 = dt2[u], d3 = dt3[u];
        float wv = vv[u];
        TANH_ACC(s0, d0)
        TANH_ACC(s1, d1)
        TANH_ACC(s2, d2)
        TANH_ACC(s3, d3)
    }

    if (uh){
        Pp[((uh-1)*4 + 0)*128 + eq] = s0;
        Pp[((uh-1)*4 + 1)*128 + eq] = s1;
        Pp[((uh-1)*4 + 2)*128 + eq] = s2;
        Pp[((uh-1)*4 + 3)*128 + eq] = s3;
    }
    __syncthreads();

    float4 p0, p1, p2, p3;
    float m0, m1, m2, m3;
    const int w = tid >> 6;              // 0/1 within the uh==0 pair
    if (uh == 0){
        #pragma unroll
        for (int p = 0; p < 3; ++p){
            float4 r;
            r = Pp[(p*4 + 0)*128 + eq]; ADD4(s0, r)
            r = Pp[(p*4 + 1)*128 + eq]; ADD4(s1, r)
            r = Pp[(p*4 + 2)*128 + eq]; ADD4(s2, r)
            r = Pp[(p*4 + 3)*128 + eq]; ADD4(s3, r)
        }
        m0 = fmaxf(fmaxf(s0.x, s0.y), fmaxf(s0.z, s0.w));
        m1 = fmaxf(fmaxf(s1.x, s1.y), fmaxf(s1.z, s1.w));
        m2 = fmaxf(fmaxf(s2.x, s2.y), fmaxf(s2.z, s2.w));
        m3 = fmaxf(fmaxf(s3.x, s3.y), fmaxf(s3.z, s3.w));
        for (int o = 32; o > 0; o >>= 1){
            m0 = fmaxf(m0, __shfl_xor(m0, o));
            m1 = fmaxf(m1, __shfl_xor(m1, o));
            m2 = fmaxf(m2, __shfl_xor(m2, o));
            m3 = fmaxf(m3, __shfl_xor(m3, o));
        }
        if ((tid & 63) == 0){
            redm[0*2 + w] = m0; redm[1*2 + w] = m1;
            redm[2*2 + w] = m2; redm[3*2 + w] = m3;
        }
    }
    __syncthreads();
    if (uh == 0){
        m0 = fmaxf(redm[0], redm[1]); m1 = fmaxf(redm[2], redm[3]);
        m2 = fmaxf(redm[4], redm[5]); m3 = fmaxf(redm[6], redm[7]);
        const float L2E = 1.4426950408889634f;
        p0.x = EXP2F((s0.x-m0)*L2E); p0.y = EXP2F((s0.y-m0)*L2E);
        p0.z = EXP2F((s0.z-m0)*L2E); p0.w = EXP2F((s0.w-m0)*L2E);
        p1.x = EXP2F((s1.x-m1)*L2E); p1.y = EXP2F((s1.y-m1)*L2E);
        p1.z = EXP2F((s1.z-m1)*L2E); p1.w = EXP2F((s1.w-m1)*L2E);
        p2.x = EXP2F((s2.x-m2)*L2E); p2.y = EXP2F((s2.y-m2)*L2E);
        p2.z = EXP2F((s2.z-m2)*L2E); p2.w = EXP2F((s2.w-m2)*L2E);
        p3.x = EXP2F((s3.x-m3)*L2E); p3.y = EXP2F((s3.y-m3)*L2E);
        p3.z = EXP2F((s3.z-m3)*L2E); p3.w = EXP2F((s3.w-m3)*L2E);
        float l0 = (p0.x+p0.y)+(p0.z+p0.w);
        float l1 = (p1.x+p1.y)+(p1.z+p1.w);
        float l2 = (p2.x+p2.y)+(p2.z+p2.w);
        float l3 = (p3.x+p3.y)+(p3.z+p3.w);
        for (int o = 32; o > 0; o >>= 1){
            l0 += __shfl_xor(l0, o); l1 += __shfl_xor(l1, o);
            l2 += __shfl_xor(l2, o); l3 += __shfl_xor(l3, o);
        }
        if ((tid & 63) == 0){
            reds[0*2 + w] = l0; reds[1*2 + w] = l1;
            reds[2*2 + w] = l2; reds[3*2 + w] = l3;
        }
    }
    __syncthreads();
    if (uh == 0){
        float i0 = RCPF(reds[0] + reds[1]);
        float i1 = RCPF(reds[2] + reds[3]);
        float i2 = RCPF(reds[4] + reds[5]);
        float i3 = RCPF(reds[6] + reds[7]);
        float4* O = (float4*)attn_out;
        O[(size_t)(b*TD + t0 + 0)*128 + eq] = make_float4(p0.x*i0, p0.y*i0, p0.z*i0, p0.w*i0);
        O[(size_t)(b*TD + t0 + 1)*128 + eq] = make_float4(p1.x*i1, p1.y*i1, p1.z*i1, p1.w*i1);
        O[(size_t)(b*TD + t0 + 2)*128 + eq] = make_float4(p2.x*i2, p2.y*i2, p2.z*i2, p2.w*i2);
        O[(size_t)(b*TD + t0 + 3)*128 + eq] = make_float4(p3.x*i3, p3.y*i3, p3.z*i3, p3.w*i3);
    }
}

// ---------------------------------------------------------------------------
// context[b,t,d] = sum_e attn[b,t,e]*enc[b,e,d].
// block = (b, t-oct, d-half), 512 threads: dq = tid&63 (d-quad within half),
// eq = tid>>6 (e-eighth, 64 e's each). LDS tree-reduce over the 8 e-groups.
// ---------------------------------------------------------------------------
__global__ __launch_bounds__(512) void context_kernel(
        const float* __restrict__ enc, const float* __restrict__ attn,
        float* __restrict__ ctx_out){
    __shared__ float4 at4[8 * 128];      // attn rows [t][e-quad], 16 KB
    __shared__ float4 red4[8 * 256];     // reduce buffer [t][4 groups][64], 32 KB
    const int tid = threadIdx.x;
    const int dh = blockIdx.x & 1;             // d-half
    const int b  = (blockIdx.x >> 1) & 3;      // ~XCD-resident batch
    const int t0 = (blockIdx.x >> 3) * 8;      // t-oct
    const int dq = tid & 63;
    const int eq = tid >> 6;

    // stage 8 attn rows (1024 float4), coalesced
    const float4* A4 = (const float4*)(attn + (size_t)(b*TD + t0) * TE);
    at4[tid]       = A4[tid];
    at4[tid + 512] = A4[tid + 512];
    __syncthreads();

    float4 acc[8];
    #pragma unroll
    for (int t = 0; t < 8; ++t) acc[t] = make_float4(0.f, 0.f, 0.f, 0.f);

    const float4* eb = (const float4*)enc + (size_t)(b*TE)*128 + dh*64 + dq;
    for (int ec = 0; ec < 16; ++ec){
        const int e0 = eq*64 + ec*4;
        float4 x0 = eb[(size_t)(e0 + 0) * 128];
        float4 x1 = eb[(size_t)(e0 + 1) * 128];
        float4 x2 = eb[(size_t)(e0 + 2) * 128];
        float4 x3 = eb[(size_t)(e0 + 3) * 128];
        #pragma unroll
        for (int t = 0; t < 8; ++t){
            float4 w = at4[t*128 + (e0 >> 2)];     // wave-uniform broadcast
            acc[t].x += x0.x*w.x + x1.x*w.y + x2.x*w.z + x3.x*w.w;
            acc[t].y += x0.y*w.x + x1.y*w.y + x2.y*w.z + x3.y*w.w;
            acc[t].z += x0.z*w.x + x1.z*w.y + x2.z*w.z + x3.z*w.w;
            acc[t].w += x0.w*w.x + x1.w*w.y + x2.w*w.z + x3.w*w.w;
        }
    }

    // tree-reduce over eq = 8 -> 1
    for (int step = 4; step >= 1; step >>= 1){
        if (eq >= step && eq < 2*step){
            #pragma unroll
            for (int t = 0; t < 8; ++t)
                red4[t*256 + (eq - step)*64 + dq] = acc[t];
        }
        __syncthreads();
        if (eq < step){
            #pragma unroll
            for (int t = 0; t < 8; ++t){
                float4 r = red4[t*256 + eq*64 + dq];
                acc[t].x += r.x; acc[t].y += r.y; acc[t].z += r.z; acc[t].w += r.w;
            }
        }
        __syncthreads();
    }

    if (eq == 0){
        float4* ob = (float4*)ctx_out + (size_t)(b*TD + t0)*128 + dh*64 + dq;
        #pragma unroll
        for (int t = 0; t < 8; ++t) ob[t*128] = acc[t];
    }
}

extern "C" void kernel_launch(void* const* d_in, const int* in_sizes, int n_in,
                              void* d_out, int out_size, void* d_ws, size_t ws_size,
                              hipStream_t stream){
    const float* enc = (const float*)d_in[0];
    const float* dec = (const float*)d_in[1];
    const float* W1w = (const float*)d_in[2];
    const float* W1b = (const float*)d_in[3];
    const float* W2w = (const float*)d_in[4];
    const float* W2b = (const float*)d_in[5];
    const float* Vw  = (const float*)d_in[6];

    float* encT = (float*)d_ws;                       // [B,U,TE] f32 = 1 MB (exp domain)

    float* outp     = (float*)d_out;                  // context [B,TD,DE]
    float* attn_out = outp + (size_t)B*TD*DE;         // attn    [B,TD,TE]

    hipLaunchKernelGGL(proj_enc_kernel, dim3(B*TE/8), dim3(512), 0, stream,
                       enc, W1w, W1b, encT);
    hipLaunchKernelGGL(score_kernel, dim3(B*TD/4), dim3(512), 0, stream,
                       encT, dec, W2w, W2b, Vw, attn_out);
    hipLaunchKernelGGL(context_kernel, dim3(B*TD/8*2), dim3(512), 0, stream,
                       enc, attn_out, outp);
}

// Round 4
// 113.825 us; speedup vs baseline: 1.0226x; 1.0226x over previous
//
#include <hip/hip_runtime.h>

#define B  4
#define TE 512
#define TD 256
#define DE 512
#define U  128

#define RCPF(x)  __builtin_amdgcn_rcpf(x)
#define EXP2F(x) __builtin_amdgcn_exp2f(x)

#define ROWFMA(ar, xr) \
    ar.x += xr.x*w0.x + xr.y*w1.x + xr.z*w2.x + xr.w*w3.x; \
    ar.y += xr.x*w0.y + xr.y*w1.y + xr.z*w2.y + xr.w*w3.y; \
    ar.z += xr.x*w0.z + xr.y*w1.z + xr.z*w2.z + xr.w*w3.z; \
    ar.w += xr.x*w0.w + xr.y*w1.w + xr.z*w2.w + xr.w*w3.w;

#define ADD4(d, s) d.x += s.x; d.y += s.y; d.z += s.z; d.w += s.w;

// ---------------------------------------------------------------------------
// Fused projections, output in EXP DOMAIN: E = exp(2 * (x@W + b)).
// blocks 0..255:   enc side, 8 rows, full u; output TRANSPOSED encT[b][u][e].
// blocks 256..511: dec side, 8 rows, ONE u-HALF (64 u) each -> 128 KB of W2
//   per block. 512 blocks round-robin over 256 CUs => each CU gets ~1 enc +
//   1 dec-half block: balanced FLOPs (1.57 MFLOP/CU) and W streams overlap
//   across co-resident blocks (the R3 in-kernel fusion serialized them).
// 256 threads, 4-way K-split over waves (ds = tid>>6), LDS partial reduce.
// ---------------------------------------------------------------------------
__global__ __launch_bounds__(256) void proj_fused_kernel(
        const float* __restrict__ enc, const float* __restrict__ dec,
        const float* __restrict__ W1w, const float* __restrict__ W1b,
        const float* __restrict__ W2w, const float* __restrict__ W2b,
        float* __restrict__ encT, float* __restrict__ decp){
    __shared__ float4 Xs[8 * 128];      // 8 rows x 512 f32 = 16 KB
    __shared__ float4 Ps[3 * 4 * 64];   // partial buffer, 12 KB (both paths fit)
    float* T = (float*)Xs;              // aliased transpose buffer
    const int tid = threadIdx.x;
    const int bid = blockIdx.x;
    const bool is_enc = bid < 256;

    const float* X; int r0; int uHalf = 0;
    if (is_enc){ r0 = bid * 8; X = enc; }
    else       { r0 = ((bid - 256) >> 1) * 8; uHalf = (bid - 256) & 1; X = dec; }

    // stage 8 rows of X (1024 float4), coalesced, 4 per thread
    const float4* Xg = (const float4*)(X + (size_t)r0 * 512);
    #pragma unroll
    for (int j = 0; j < 4; ++j)
        Xs[j * 256 + tid] = Xg[j * 256 + tid];
    __syncthreads();

    const float C2 = 2.8853900817779268f;  // 2*log2(e)

    if (is_enc){
        const int q  = tid & 31;          // u-quad: u0 = 4q
        const int g  = (tid >> 5) & 1;    // rows g, g+2, g+4, g+6
        const int ds = tid >> 6;          // d-quarter, one per wave
        const float4* W4 = (const float4*)W1w;   // row d = 32 float4

        float4 a0, a1, a2, a3;
        a0 = a1 = a2 = a3 = make_float4(0.f, 0.f, 0.f, 0.f);

        const int dbase = ds * 128;
        #pragma unroll 2
        for (int dd = 0; dd < 128; dd += 4){
            const int d0 = dbase + dd;
            const int xq = d0 >> 2;
            float4 x0 = Xs[(g + 0) * 128 + xq];     // LDS broadcast
            float4 x1 = Xs[(g + 2) * 128 + xq];
            float4 x2 = Xs[(g + 4) * 128 + xq];
            float4 x3 = Xs[(g + 6) * 128 + xq];
            float4 w0 = W4[(d0 + 0) * 32 + q];
            float4 w1 = W4[(d0 + 1) * 32 + q];
            float4 w2 = W4[(d0 + 2) * 32 + q];
            float4 w3 = W4[(d0 + 3) * 32 + q];
            ROWFMA(a0, x0)
            ROWFMA(a1, x1)
            ROWFMA(a2, x2)
            ROWFMA(a3, x3)
        }

        const int slot = (g << 5) | q;
        if (ds){
            Ps[((ds-1)*4 + 0)*64 + slot] = a0;
            Ps[((ds-1)*4 + 1)*64 + slot] = a1;
            Ps[((ds-1)*4 + 2)*64 + slot] = a2;
            Ps[((ds-1)*4 + 3)*64 + slot] = a3;
        }
        __syncthreads();                     // partials ready; Xs reads done

        if (ds == 0){
            #pragma unroll
            for (int p = 0; p < 3; ++p){
                float4 r;
                r = Ps[(p*4 + 0)*64 + slot]; ADD4(a0, r)
                r = Ps[(p*4 + 1)*64 + slot]; ADD4(a1, r)
                r = Ps[(p*4 + 2)*64 + slot]; ADD4(a2, r)
                r = Ps[(p*4 + 3)*64 + slot]; ADD4(a3, r)
            }
            float4 bq = ((const float4*)W1b)[q];
            ADD4(a0, bq) ADD4(a1, bq) ADD4(a2, bq) ADD4(a3, bq)

            a0.x = EXP2F(a0.x*C2); a0.y = EXP2F(a0.y*C2); a0.z = EXP2F(a0.z*C2); a0.w = EXP2F(a0.w*C2);
            a1.x = EXP2F(a1.x*C2); a1.y = EXP2F(a1.y*C2); a1.z = EXP2F(a1.z*C2); a1.w = EXP2F(a1.w*C2);
            a2.x = EXP2F(a2.x*C2); a2.y = EXP2F(a2.y*C2); a2.z = EXP2F(a2.z*C2); a2.w = EXP2F(a2.w*C2);
            a3.x = EXP2F(a3.x*C2); a3.y = EXP2F(a3.y*C2); a3.z = EXP2F(a3.z*C2); a3.w = EXP2F(a3.w*C2);

            // T[u][e_local], u-stride 9 (pad breaks power-of-2 banks)
            T[(4*q+0)*9 + g + 0] = a0.x; T[(4*q+1)*9 + g + 0] = a0.y;
            T[(4*q+2)*9 + g + 0] = a0.z; T[(4*q+3)*9 + g + 0] = a0.w;
            T[(4*q+0)*9 + g + 2] = a1.x; T[(4*q+1)*9 + g + 2] = a1.y;
            T[(4*q+2)*9 + g + 2] = a1.z; T[(4*q+3)*9 + g + 2] = a1.w;
            T[(4*q+0)*9 + g + 4] = a2.x; T[(4*q+1)*9 + g + 4] = a2.y;
            T[(4*q+2)*9 + g + 4] = a2.z; T[(4*q+3)*9 + g + 4] = a2.w;
            T[(4*q+0)*9 + g + 6] = a3.x; T[(4*q+1)*9 + g + 6] = a3.y;
            T[(4*q+2)*9 + g + 6] = a3.z; T[(4*q+3)*9 + g + 6] = a3.w;
        }
        __syncthreads();                     // T ready

        if (tid < 128){
            const int u  = tid;
            const int bb = r0 >> 9;          // 512 rows per batch
            const int et = r0 & 511;         // e-tile base
            float4 lo = make_float4(T[u*9+0], T[u*9+1], T[u*9+2], T[u*9+3]);
            float4 hi = make_float4(T[u*9+4], T[u*9+5], T[u*9+6], T[u*9+7]);
            float4* row = (float4*)encT + (size_t)(bb*U + u)*128 + (et >> 2);
            row[0] = lo; row[1] = hi;
        }
    } else {
        // ---- dec u-half block: 8 rows, u-quads [uHalf*16, uHalf*16+16)
        const int q16 = tid & 15;            // u-quad within half
        const int gg  = (tid >> 4) & 3;      // rows gg, gg+4
        const int ds  = tid >> 6;            // d-quarter, one per wave
        const int wq  = uHalf * 16 + q16;    // global u-quad
        const float4* W4 = (const float4*)W2w;

        float4 a0 = make_float4(0.f, 0.f, 0.f, 0.f);
        float4 a1 = make_float4(0.f, 0.f, 0.f, 0.f);

        const int dbase = ds * 128;
        #pragma unroll 2
        for (int dd = 0; dd < 128; dd += 4){
            const int d0 = dbase + dd;
            const int xq = d0 >> 2;
            float4 x0 = Xs[(gg + 0) * 128 + xq];    // LDS broadcast
            float4 x1 = Xs[(gg + 4) * 128 + xq];
            float4 w0 = W4[(d0 + 0) * 32 + wq];
            float4 w1 = W4[(d0 + 1) * 32 + wq];
            float4 w2 = W4[(d0 + 2) * 32 + wq];
            float4 w3 = W4[(d0 + 3) * 32 + wq];
            ROWFMA(a0, x0)
            ROWFMA(a1, x1)
        }

        if (ds){
            Ps[((ds-1)*8 + gg    )*16 + q16] = a0;
            Ps[((ds-1)*8 + gg + 4)*16 + q16] = a1;
        }
        __syncthreads();

        if (ds == 0){                        // tid<64 covers all (gg,q16)
            #pragma unroll
            for (int p = 0; p < 3; ++p){
                float4 r;
                r = Ps[(p*8 + gg    )*16 + q16]; ADD4(a0, r)
                r = Ps[(p*8 + gg + 4)*16 + q16]; ADD4(a1, r)
            }
            float4 bq = ((const float4*)W2b)[wq];
            ADD4(a0, bq) ADD4(a1, bq)
            a0.x = EXP2F(a0.x*C2); a0.y = EXP2F(a0.y*C2); a0.z = EXP2F(a0.z*C2); a0.w = EXP2F(a0.w*C2);
            a1.x = EXP2F(a1.x*C2); a1.y = EXP2F(a1.y*C2); a1.z = EXP2F(a1.z*C2); a1.w = EXP2F(a1.w*C2);
            float4* D = (float4*)decp;
            D[(size_t)(r0 + gg    ) * 32 + wq] = a0;
            D[(size_t)(r0 + gg + 4) * 32 + wq] = a1;
        }
    }
}

// ---------------------------------------------------------------------------
// Score + softmax, exp-factorized tanh:
//   logits[e] = sum_u (-2*V_u) * rcp(Ea[u][e]*Ed[t][u] + 1)
// (the e-independent constant cancels in softmax).
// block = (b, t-quad), 512 threads. Main loop: each thread handles ALL 4 t's
// for its 4 e's; u quarter-split across wave-pairs (uh). Tail: ALL wave-pairs
// participate -- pair uh combines partials and runs softmax for t = uh
// (R2 left 6 of 8 waves idle here).
// ---------------------------------------------------------------------------
#define TANH_ACC(s, dv) \
    s.x += wv * RCPF(fmaf(A.x, dv, 1.0f)); \
    s.y += wv * RCPF(fmaf(A.y, dv, 1.0f)); \
    s.z += wv * RCPF(fmaf(A.z, dv, 1.0f)); \
    s.w += wv * RCPF(fmaf(A.w, dv, 1.0f));

__global__ __launch_bounds__(512) void score_kernel(
        const float* __restrict__ encT, const float* __restrict__ decp,
        const float* __restrict__ Vw, float* __restrict__ attn_out){
    __shared__ float4 dp4[128];          // Ed rows t0..t0+3 (4 x 128 f32)
    __shared__ float4 vv4[32];           // -2*V (128 f32)
    __shared__ float4 Pp[4 * 4 * 128];   // partials [uh][t][eq] = 32 KB
    __shared__ float redm[8], reds[8];   // [t][wave-half]
    const float* dpf = (const float*)dp4;
    const float* vvf = (const float*)vv4;
    const int tid = threadIdx.x;
    const int b  = blockIdx.x >> 6;
    const int t0 = (blockIdx.x & 63) * 4;

    if (tid < 128){
        dp4[tid] = ((const float4*)decp)[(size_t)(b*TD + t0 + (tid>>5))*32 + (tid&31)];
    } else if (tid < 160){
        float4 v = ((const float4*)Vw)[tid - 128];
        vv4[tid - 128] = make_float4(-2.f*v.x, -2.f*v.y, -2.f*v.z, -2.f*v.w);
    }
    __syncthreads();

    const int uh = tid >> 7;         // u-quarter 0..3 (wave-pair uniform)
    const int eq = tid & 127;        // e-quad: e0 = 4*eq
    const int u0 = uh * 32;

    const float4* E  = (const float4*)encT + (size_t)b*U*128 + (size_t)u0*128 + eq;
    const float* dt0 = dpf + 0*128 + u0;
    const float* dt1 = dpf + 1*128 + u0;
    const float* dt2 = dpf + 2*128 + u0;
    const float* dt3 = dpf + 3*128 + u0;
    const float* vv  = vvf + u0;

    float4 s0, s1, s2, s3;
    s0 = s1 = s2 = s3 = make_float4(0.f, 0.f, 0.f, 0.f);

    #pragma unroll 4
    for (int u = 0; u < 32; ++u){
        float4 A = E[(size_t)u * 128];        // coalesced across e-lanes
        float d0 = dt0[u], d1 = dt1[u], d2 = dt2[u], d3 = dt3[u];
        float wv = vv[u];
        TANH_ACC(s0, d0)
        TANH_ACC(s1, d1)
        TANH_ACC(s2, d2)
        TANH_ACC(s3, d3)
    }

    Pp[(uh*4 + 0)*128 + eq] = s0;
    Pp[(uh*4 + 1)*128 + eq] = s1;
    Pp[(uh*4 + 2)*128 + eq] = s2;
    Pp[(uh*4 + 3)*128 + eq] = s3;
    __syncthreads();

    // wave-pair uh owns t = uh; combine in fixed order (bit-identical to R2)
    const int t = uh;
    float4 s = Pp[(0*4 + t)*128 + eq];
    {
        float4 r;
        r = Pp[(1*4 + t)*128 + eq]; ADD4(s, r)
        r = Pp[(2*4 + t)*128 + eq]; ADD4(s, r)
        r = Pp[(3*4 + t)*128 + eq]; ADD4(s, r)
    }

    float m = fmaxf(fmaxf(s.x, s.y), fmaxf(s.z, s.w));
    for (int o = 32; o > 0; o >>= 1) m = fmaxf(m, __shfl_xor(m, o));
    const int half = (tid >> 6) & 1;
    if ((tid & 63) == 0) redm[t*2 + half] = m;
    __syncthreads();
    m = fmaxf(redm[t*2], redm[t*2 + 1]);

    const float L2E = 1.4426950408889634f;
    float4 p;
    p.x = EXP2F((s.x - m) * L2E);
    p.y = EXP2F((s.y - m) * L2E);
    p.z = EXP2F((s.z - m) * L2E);
    p.w = EXP2F((s.w - m) * L2E);
    float l = (p.x + p.y) + (p.z + p.w);
    for (int o = 32; o > 0; o >>= 1) l += __shfl_xor(l, o);
    if ((tid & 63) == 0) reds[t*2 + half] = l;
    __syncthreads();
    float inv = RCPF(reds[t*2] + reds[t*2 + 1]);

    ((float4*)attn_out)[(size_t)(b*TD + t0 + t)*128 + eq] =
        make_float4(p.x*inv, p.y*inv, p.z*inv, p.w*inv);
}

// ---------------------------------------------------------------------------
// context[b,t,d] = sum_e attn[b,t,e]*enc[b,e,d].
// block = (b, t-oct, d-half), 512 threads: dq = tid&63 (d-quad within half),
// eq = tid>>6 (e-eighth, 64 e's each). LDS tree-reduce over the 8 e-groups.
// ---------------------------------------------------------------------------
__global__ __launch_bounds__(512) void context_kernel(
        const float* __restrict__ enc, const float* __restrict__ attn,
        float* __restrict__ ctx_out){
    __shared__ float4 at4[8 * 128];      // attn rows [t][e-quad], 16 KB
    __shared__ float4 red4[8 * 256];     // reduce buffer [t][4 groups][64], 32 KB
    const int tid = threadIdx.x;
    const int dh = blockIdx.x & 1;             // d-half
    const int b  = (blockIdx.x >> 1) & 3;      // ~XCD-resident batch
    const int t0 = (blockIdx.x >> 3) * 8;      // t-oct
    const int dq = tid & 63;
    const int eq = tid >> 6;

    // stage 8 attn rows (1024 float4), coalesced
    const float4* A4 = (const float4*)(attn + (size_t)(b*TD + t0) * TE);
    at4[tid]       = A4[tid];
    at4[tid + 512] = A4[tid + 512];
    __syncthreads();

    float4 acc[8];
    #pragma unroll
    for (int t = 0; t < 8; ++t) acc[t] = make_float4(0.f, 0.f, 0.f, 0.f);

    const float4* eb = (const float4*)enc + (size_t)(b*TE)*128 + dh*64 + dq;
    for (int ec = 0; ec < 16; ++ec){
        const int e0 = eq*64 + ec*4;
        float4 x0 = eb[(size_t)(e0 + 0) * 128];
        float4 x1 = eb[(size_t)(e0 + 1) * 128];
        float4 x2 = eb[(size_t)(e0 + 2) * 128];
        float4 x3 = eb[(size_t)(e0 + 3) * 128];
        #pragma unroll
        for (int t = 0; t < 8; ++t){
            float4 w = at4[t*128 + (e0 >> 2)];     // wave-uniform broadcast
            acc[t].x += x0.x*w.x + x1.x*w.y + x2.x*w.z + x3.x*w.w;
            acc[t].y += x0.y*w.x + x1.y*w.y + x2.y*w.z + x3.y*w.w;
            acc[t].z += x0.z*w.x + x1.z*w.y + x2.z*w.z + x3.z*w.w;
            acc[t].w += x0.w*w.x + x1.w*w.y + x2.w*w.z + x3.w*w.w;
        }
    }

    // tree-reduce over eq = 8 -> 1
    for (int step = 4; step >= 1; step >>= 1){
        if (eq >= step && eq < 2*step){
            #pragma unroll
            for (int t = 0; t < 8; ++t)
                red4[t*256 + (eq - step)*64 + dq] = acc[t];
        }
        __syncthreads();
        if (eq < step){
            #pragma unroll
            for (int t = 0; t < 8; ++t){
                float4 r = red4[t*256 + eq*64 + dq];
                acc[t].x += r.x; acc[t].y += r.y; acc[t].z += r.z; acc[t].w += r.w;
            }
        }
        __syncthreads();
    }

    if (eq == 0){
        float4* ob = (float4*)ctx_out + (size_t)(b*TD + t0)*128 + dh*64 + dq;
        #pragma unroll
        for (int t = 0; t < 8; ++t) ob[t*128] = acc[t];
    }
}

extern "C" void kernel_launch(void* const* d_in, const int* in_sizes, int n_in,
                              void* d_out, int out_size, void* d_ws, size_t ws_size,
                              hipStream_t stream){
    const float* enc = (const float*)d_in[0];
    const float* dec = (const float*)d_in[1];
    const float* W1w = (const float*)d_in[2];
    const float* W1b = (const float*)d_in[3];
    const float* W2w = (const float*)d_in[4];
    const float* W2b = (const float*)d_in[5];
    const float* Vw  = (const float*)d_in[6];

    float* encT = (float*)d_ws;                       // [B,U,TE] f32 = 1 MB (exp domain)
    float* decp = encT + (size_t)B*U*TE;              // [B*TD,U] f32 = 0.5 MB (exp domain)

    float* outp     = (float*)d_out;                  // context [B,TD,DE]
    float* attn_out = outp + (size_t)B*TD*DE;         // attn    [B,TD,TE]

    hipLaunchKernelGGL(proj_fused_kernel, dim3(512), dim3(256), 0, stream,
                       enc, dec, W1w, W1b, W2w, W2b, encT, decp);
    hipLaunchKernelGGL(score_kernel, dim3(B*TD/4), dim3(512), 0, stream,
                       encT, decp, Vw, attn_out);
    hipLaunchKernelGGL(context_kernel, dim3(B*TD/8*2), dim3(512), 0, stream,
                       enc, attn_out, outp);
}